// Round 16
// baseline (127.116 us; speedup 1.0000x reference)
//
#include <hip/hip_runtime.h>
#include <hip/hip_bf16.h>

// ALiBi attention, B=8 L=1024 H=8 E=64, fp32 in/out, bf16 MFMA inside.
// Outputs: V [B,L,H,E] then series [B,H,L,L] concatenated in d_out.
// R16 = R15 (fused single-QK pass) + the O-normalization fix: PV output
// rows are q = 4*kg+r (not q = col), so the O-write needs per-ROW 1/z,
// broadcast via a small LDS table zinv[qs][16]. P store path unchanged.
// 8-wave blocks (4 q-subtiles x 2 key-halves); loop 1 = stage K/V (dbuf)
// + QK^T + e=exp2(u-32) (unnormalized) -> z + packed bf16 pw[] + PV;
// loop 2 = pure store stream P = e * (1/z).

typedef short short8 __attribute__((ext_vector_type(8)));
typedef short short4v __attribute__((ext_vector_type(4)));
typedef float f32x4 __attribute__((ext_vector_type(4)));
typedef unsigned short u16x4 __attribute__((ext_vector_type(4)));

#define B_ 8
#define L_ 1024
#define H_ 8
#define E_ 64
#define RSTRIDE (H_ * E_)       // 512 floats between seq rows
#define QBLK 64                 // 4 q-subtiles x 16 rows
#define CHUNK 64                // keys per chunk
#define NCH (L_ / CHUNK)        // 16 total; 8 per key-half
#define CHUNK_USH (CHUNK * E_)  // 4096 ushorts = 8KB per chunk tile

__device__ __forceinline__ unsigned short f2bf(float f) {
  return __builtin_bit_cast(unsigned short, __float2bfloat16(f));
}
__device__ __forceinline__ float bf2f(unsigned int ubits) {
  return __builtin_bit_cast(float, ubits << 16);
}
__device__ __forceinline__ short8 ldfrag(const float* p) {
  float4 a = *reinterpret_cast<const float4*>(p);
  float4 b = *reinterpret_cast<const float4*>(p + 4);
  return (short8){(short)f2bf(a.x), (short)f2bf(a.y), (short)f2bf(a.z),
                  (short)f2bf(a.w), (short)f2bf(b.x), (short)f2bf(b.y),
                  (short)f2bf(b.z), (short)f2bf(b.w)};
}

__device__ __forceinline__ f32x4 mfma16(short4v a, short4v b, f32x4 c) {
#if __has_builtin(__builtin_amdgcn_mfma_f32_16x16x16bf16_1k)
  return __builtin_amdgcn_mfma_f32_16x16x16bf16_1k(a, b, c, 0, 0, 0);
#else
  asm volatile(
      "s_nop 1\n\t"
      "v_mfma_f32_16x16x16_bf16 %0, %1, %2, %0\n\t"
      "s_nop 2"
      : "+v"(c)
      : "v"(a), "v"(b));
  return c;
#endif
}

__device__ __forceinline__ void gld16(const unsigned short* g,
                                      unsigned short* l) {
  __builtin_amdgcn_global_load_lds(
      (const __attribute__((address_space(1))) unsigned int*)g,
      (__attribute__((address_space(3))) unsigned int*)l, 16, 0, 0);
}

#define BAR_VM(N)                                         \
  {                                                       \
    asm volatile("s_waitcnt vmcnt(" #N ")" ::: "memory"); \
    __builtin_amdgcn_s_barrier();                         \
    __builtin_amdgcn_sched_barrier(0);                    \
  }
#define PIN() __builtin_amdgcn_sched_barrier(0)

// ---- prep: scratch in gload-linear swizzled block order (as R12) ----
__global__ __launch_bounds__(256, 4) void prep_kv(
    const float* __restrict__ Kg, const float* __restrict__ Vg,
    unsigned short* __restrict__ Kbf, unsigned short* __restrict__ VTbf) {
  __shared__ unsigned short vt[64 * 64];  // V^T tile in swizzled space

  const int t = threadIdx.x;
  const int id = blockIdx.x;
  const int bh = id & 63;  // id%8 = h -> same XCD as consumers
  const int sc = id >> 6;  // chunk 0..15
  const int h = bh & 7, b = bh >> 3;
  const int s0 = sc * CHUNK;

  const float* Kb = Kg + ((size_t)b * L_ + s0) * RSTRIDE + h * E_;
  const float* Vb = Vg + ((size_t)b * L_ + s0) * RSTRIDE + h * E_;
  unsigned short* Ko = Kbf + (size_t)(bh * NCH + sc) * CHUNK_USH;
  unsigned short* Vo = VTbf + (size_t)(bh * NCH + sc) * CHUNK_USH;

#pragma unroll
  for (int i = 0; i < 2; ++i) {
    const int j = t + 256 * i;  // 512 16B-blocks
    const int s = j >> 3;
    const int e8 = (j & 7) ^ (s & 7);
    const float* kp = Kb + (size_t)s * RSTRIDE + 8 * e8;
    float4 a = *reinterpret_cast<const float4*>(kp);
    float4 c = *reinterpret_cast<const float4*>(kp + 4);
    *reinterpret_cast<u16x4*>(&Ko[j * 8]) =
        (u16x4){f2bf(a.x), f2bf(a.y), f2bf(a.z), f2bf(a.w)};
    *reinterpret_cast<u16x4*>(&Ko[j * 8 + 4]) =
        (u16x4){f2bf(c.x), f2bf(c.y), f2bf(c.z), f2bf(c.w)};
  }
  {
    const int e = t & 63, w = t >> 6;
#pragma unroll
    for (int i = 0; i < 4; ++i) {
      const int s4 = 4 * w + 16 * i;
      const float* vp = Vb + (size_t)s4 * RSTRIDE + e;
      u16x4 u = {f2bf(vp[0]), f2bf(vp[RSTRIDE]), f2bf(vp[2 * RSTRIDE]),
                 f2bf(vp[3 * RSTRIDE])};
      *reinterpret_cast<u16x4*>(
          &vt[e * 64 + (((s4 >> 3) ^ (e & 7)) << 3) + (s4 & 7)]) = u;
    }
  }
  __syncthreads();
#pragma unroll
  for (int i = 0; i < 2; ++i) {
    const int j = t + 256 * i;  // swizzled space is block-linear
    u16x4 u0 = *reinterpret_cast<const u16x4*>(&vt[j * 8]);
    u16x4 u1 = *reinterpret_cast<const u16x4*>(&vt[j * 8 + 4]);
    *reinterpret_cast<u16x4*>(&Vo[j * 8]) = u0;
    *reinterpret_cast<u16x4*>(&Vo[j * 8 + 4]) = u1;
  }
}

// ---- main: fused, 8 waves = 4 qs x 2 kh, P register-resident ----
__global__ __launch_bounds__(512, 4) void alibi_attn(
    const float* __restrict__ Qg, const unsigned short* __restrict__ Kbf,
    const unsigned short* __restrict__ VTbf, float* __restrict__ Vout,
    float* __restrict__ Pout) {
  __shared__ unsigned short sK[2][2][CHUNK_USH];  // [kh][dbuf] 32KB
  __shared__ unsigned short sV[2][2][CHUNK_USH];  // [kh][dbuf] 32KB
  __shared__ float zbuf[2][4][16];                // [kh][qs][q-col]
  __shared__ float zinv[4][16];                   // [qs][q-row] = 1/z

  const int t = threadIdx.x;
  const int lane = t & 63;
  const int w = t >> 6;   // 0..7
  const int qs = w & 3;   // q-subtile
  const int kh = w >> 2;  // key half: chunks 8*kh .. 8*kh+7
  const int col = lane & 15;
  const int kg = lane >> 4;

  const int id = blockIdx.x;  // id%8 = h -> XCD-pinned scratch in L2
  const int qb = id >> 6;
  const int bh = id & 63;
  const int h = bh & 7;
  const int b = bh >> 3;
  const int q0 = qb * QBLK;

  const float sc_l2e = 0.125f * 1.44269504f;
  const float sl_l2e = exp2f(-(float)(h + 1) * 0.125f) * 1.44269504f;

  const unsigned short* Kc = Kbf + (size_t)bh * NCH * CHUNK_USH;
  const unsigned short* Vc = VTbf + (size_t)bh * NCH * CHUNK_USH;

  // Q B-fragments: q-row = col, k = 8*kg + j (+32 for second slice)
  short8 qf0, qf1;
  {
    const float* qp =
        Qg + ((size_t)b * L_ + q0 + 16 * qs + col) * RSTRIDE + h * E_ + 8 * kg;
    qf0 = ldfrag(qp);
    qf1 = ldfrag(qp + 32);
  }

  const float kbias0 = sl_l2e * (float)(4 * kg - 1023) - 32.0f;

#define STAGE(srcbase, c, dst)                                       \
  {                                                                  \
    const unsigned short* src = (srcbase) + (size_t)(c)*CHUNK_USH;   \
    _Pragma("unroll") for (int i = 0; i < 2; ++i) {                  \
      const int seg = i * 4 + qs;                                    \
      gld16(src + (size_t)(seg * 64 + lane) * 8, (dst) + seg * 512); \
    }                                                                \
  }

  // ===== Loop 1: QK^T + exp + z + PV (unnormalized), single pass =====
  float z0 = 0.f, z1 = 0.f;
  f32x4 oacc[4];
#pragma unroll
  for (int et = 0; et < 4; ++et) oacc[et] = (f32x4){0.f, 0.f, 0.f, 0.f};
  uint2 pw[8][4];  // packed bf16 e-values: [chunk][kt], all static indices

  STAGE(Kc, 8 * kh, sK[kh][0]);
  STAGE(Vc, 8 * kh, sV[kh][0]);
  PIN();
  BAR_VM(0);
#pragma unroll
  for (int c = 0; c < 8; ++c) {
    if (c + 1 < 8) {
      STAGE(Kc, 8 * kh + c + 1, sK[kh][(c + 1) & 1]);
      STAGE(Vc, 8 * kh + c + 1, sV[kh][(c + 1) & 1]);
      PIN();  // issue-early; drained after compute at the barrier
    }
    const int cc = 8 * kh + c;
    const unsigned short* kb = sK[kh][c & 1];
    const unsigned short* vb = sV[kh][c & 1];
#pragma unroll
    for (int kt = 0; kt < 4; ++kt) {
      const int row = 16 * kt + col;
      short8 k0 = *reinterpret_cast<const short8*>(
          &kb[row * 64 + ((kg ^ (row & 7)) << 3)]);
      short8 k1 = *reinterpret_cast<const short8*>(
          &kb[row * 64 + (((kg + 4) ^ (row & 7)) << 3)]);
      f32x4 acc = {0.f, 0.f, 0.f, 0.f};
      acc = __builtin_amdgcn_mfma_f32_16x16x32_bf16(k0, qf0, acc, 0, 0, 0);
      acc = __builtin_amdgcn_mfma_f32_16x16x32_bf16(k1, qf1, acc, 0, 0, 0);
      const float base = fmaf((float)(CHUNK * cc + 16 * kt), sl_l2e, kbias0);
      float e0 = __builtin_amdgcn_exp2f(fmaf(acc[0], sc_l2e, base));
      float e1 = __builtin_amdgcn_exp2f(fmaf(acc[1], sc_l2e, base + sl_l2e));
      float e2 =
          __builtin_amdgcn_exp2f(fmaf(acc[2], sc_l2e, base + 2.f * sl_l2e));
      float e3 =
          __builtin_amdgcn_exp2f(fmaf(acc[3], sc_l2e, base + 3.f * sl_l2e));
      z0 += e0 + e1;
      z1 += e2 + e3;
      const unsigned int b0 = f2bf(e0), b1 = f2bf(e1);
      const unsigned int b2 = f2bf(e2), b3 = f2bf(e3);
      pw[c][kt] = make_uint2(b0 | (b1 << 16), b2 | (b3 << 16));
      // PV with unnormalized e (A-frag k = 4*kg + j == this lane's keys)
      short4v pa = {(short)(unsigned short)b0, (short)(unsigned short)b1,
                    (short)(unsigned short)b2, (short)(unsigned short)b3};
#pragma unroll
      for (int et = 0; et < 4; ++et) {
        const int e = 16 * et + col;
        const int g0 = 2 * kt + (kg >> 1);
        short4v vf = *reinterpret_cast<const short4v*>(
            &vb[e * 64 + ((g0 ^ (e & 7)) << 3) + 4 * (kg & 1)]);
        oacc[et] = mfma16(pa, vf, oacc[et]);
      }
    }
    BAR_VM(0);  // loads of chunk c+1 had the whole compute to land
  }

  // ===== combine z across kg (in-wave) and kh (via LDS) =====
  // NOTE: lane's z / e / P are for q = col (QK D-frag column).
  float z = z0 + z1;
  z += __shfl_xor(z, 16, 64);
  z += __shfl_xor(z, 32, 64);  // all lanes: z-half for q = col
  if (kg == 0) zbuf[kh][qs][col] = z;
  __syncthreads();
  const float minv = 1.0f / (zbuf[0][qs][col] + zbuf[1][qs][col]);  // q = col

  // broadcast per-ROW 1/z for the O path (PV output rows are q = 4*kg+r)
  if (kh == 0 && kg == 0) zinv[qs][col] = minv;

  // ===== combine O across kh (reuse sK as obuf), write O =====
  float* obuf = reinterpret_cast<float*>(&sK[0][0][0]);  // [qs][16][64]
  if (kh == 1) {
#pragma unroll
    for (int et = 0; et < 4; ++et)
#pragma unroll
      for (int r = 0; r < 4; ++r)
        obuf[(qs * 16 + 4 * kg + r) * 64 + 16 * et + col] = oacc[et][r];
  }
  __syncthreads();
  if (kh == 0) {
    float minvR[4];
#pragma unroll
    for (int r = 0; r < 4; ++r) minvR[r] = zinv[qs][4 * kg + r];
    float* Vo = Vout + (((size_t)b * L_ + q0 + 16 * qs) * H_ + h) * E_;
#pragma unroll
    for (int et = 0; et < 4; ++et) {
#pragma unroll
      for (int r = 0; r < 4; ++r) {
        const float o =
            (oacc[et][r] + obuf[(qs * 16 + 4 * kg + r) * 64 + 16 * et + col]) *
            minvR[r];
        __builtin_nontemporal_store(
            o, &Vo[(4 * kg + r) * RSTRIDE + 16 * et + col]);
      }
    }
  }

  // ===== Loop 2: pure store stream, P = e * minv (q = col: minv is right) ==
  float* Pb = Pout + ((size_t)(b * H_ + h) * L_ + q0 + 16 * qs + col) * L_ +
              4 * kg;
#pragma unroll
  for (int c = 0; c < 8; ++c) {
    const int cc = 8 * kh + c;
#pragma unroll
    for (int kt = 0; kt < 4; ++kt) {
      const uint2 u = pw[c][kt];
      f32x4 out;
      out[0] = bf2f(u.x & 0xffffu) * minv;
      out[1] = bf2f(u.x >> 16) * minv;
      out[2] = bf2f(u.y & 0xffffu) * minv;
      out[3] = bf2f(u.y >> 16) * minv;
      __builtin_nontemporal_store(
          out, reinterpret_cast<f32x4*>(Pb + CHUNK * cc + 16 * kt));
    }
  }
}

extern "C" void kernel_launch(void* const* d_in, const int* in_sizes, int n_in,
                              void* d_out, int out_size, void* d_ws,
                              size_t ws_size, hipStream_t stream) {
  const float* Q = (const float*)d_in[0];
  const float* K = (const float*)d_in[1];
  const float* V = (const float*)d_in[2];
  float* out = (float*)d_out;
  float* Vo = out;                              // [B,L,H,E]
  float* Po = out + (size_t)B_ * L_ * H_ * E_;  // [B,H,L,L]
  unsigned short* Kbf = (unsigned short*)d_ws;  // 8 MB
  unsigned short* VTbf = Kbf + (size_t)B_ * H_ * L_ * E_;  // 8 MB
  hipLaunchKernelGGL(prep_kv, dim3(NCH * B_ * H_), dim3(256), 0, stream, K, V,
                     Kbf, VTbf);
  hipLaunchKernelGGL(alibi_attn, dim3((L_ / QBLK) * H_ * B_), dim3(512), 0,
                     stream, Q, Kbf, VTbf, Vo, Po);
}

// Round 17
// 112.277 us; speedup vs baseline: 1.1322x; 1.1322x over previous
//
#include <hip/hip_runtime.h>
#include <hip/hip_bf16.h>

// ALiBi attention, B=8 L=1024 H=8 E=64, fp32 in/out, bf16 MFMA inside.
// Outputs: V [B,L,H,E] then series [B,H,L,L] concatenated in d_out.
// R17 = R16 with two reverts-to-R12-behavior:
//  (1) __launch_bounds__(512,2): VGPR cap 256 (was 128 -> spills suspected);
//      occupancy unchanged (LDS-limited to 2 blocks/CU anyway).
//  (2) loop-2 P stores are PLAIN (not nontemporal) so L2 merges the 64B
//      quarter-line segments into full lines (R6 lesson).
// Structure: fused single-QK pass; 8 waves = 4 q-subtiles x 2 key-halves;
// loop 1 = stage K/V (dbuf) + QK^T + e=exp2(u-32) -> z + packed bf16 pw[]
// + PV (unnormalized); loop 2 = pure store stream P = e/z.

typedef short short8 __attribute__((ext_vector_type(8)));
typedef short short4v __attribute__((ext_vector_type(4)));
typedef float f32x4 __attribute__((ext_vector_type(4)));
typedef unsigned short u16x4 __attribute__((ext_vector_type(4)));

#define B_ 8
#define L_ 1024
#define H_ 8
#define E_ 64
#define RSTRIDE (H_ * E_)       // 512 floats between seq rows
#define QBLK 64                 // 4 q-subtiles x 16 rows
#define CHUNK 64                // keys per chunk
#define NCH (L_ / CHUNK)        // 16 total; 8 per key-half
#define CHUNK_USH (CHUNK * E_)  // 4096 ushorts = 8KB per chunk tile

__device__ __forceinline__ unsigned short f2bf(float f) {
  return __builtin_bit_cast(unsigned short, __float2bfloat16(f));
}
__device__ __forceinline__ float bf2f(unsigned int ubits) {
  return __builtin_bit_cast(float, ubits << 16);
}
__device__ __forceinline__ short8 ldfrag(const float* p) {
  float4 a = *reinterpret_cast<const float4*>(p);
  float4 b = *reinterpret_cast<const float4*>(p + 4);
  return (short8){(short)f2bf(a.x), (short)f2bf(a.y), (short)f2bf(a.z),
                  (short)f2bf(a.w), (short)f2bf(b.x), (short)f2bf(b.y),
                  (short)f2bf(b.z), (short)f2bf(b.w)};
}

__device__ __forceinline__ f32x4 mfma16(short4v a, short4v b, f32x4 c) {
#if __has_builtin(__builtin_amdgcn_mfma_f32_16x16x16bf16_1k)
  return __builtin_amdgcn_mfma_f32_16x16x16bf16_1k(a, b, c, 0, 0, 0);
#else
  asm volatile(
      "s_nop 1\n\t"
      "v_mfma_f32_16x16x16_bf16 %0, %1, %2, %0\n\t"
      "s_nop 2"
      : "+v"(c)
      : "v"(a), "v"(b));
  return c;
#endif
}

__device__ __forceinline__ void gld16(const unsigned short* g,
                                      unsigned short* l) {
  __builtin_amdgcn_global_load_lds(
      (const __attribute__((address_space(1))) unsigned int*)g,
      (__attribute__((address_space(3))) unsigned int*)l, 16, 0, 0);
}

#define BAR_VM(N)                                         \
  {                                                       \
    asm volatile("s_waitcnt vmcnt(" #N ")" ::: "memory"); \
    __builtin_amdgcn_s_barrier();                         \
    __builtin_amdgcn_sched_barrier(0);                    \
  }
#define PIN() __builtin_amdgcn_sched_barrier(0)

// ---- prep: scratch in gload-linear swizzled block order (as R12) ----
__global__ __launch_bounds__(256, 4) void prep_kv(
    const float* __restrict__ Kg, const float* __restrict__ Vg,
    unsigned short* __restrict__ Kbf, unsigned short* __restrict__ VTbf) {
  __shared__ unsigned short vt[64 * 64];  // V^T tile in swizzled space

  const int t = threadIdx.x;
  const int id = blockIdx.x;
  const int bh = id & 63;  // id%8 = h -> same XCD as consumers
  const int sc = id >> 6;  // chunk 0..15
  const int h = bh & 7, b = bh >> 3;
  const int s0 = sc * CHUNK;

  const float* Kb = Kg + ((size_t)b * L_ + s0) * RSTRIDE + h * E_;
  const float* Vb = Vg + ((size_t)b * L_ + s0) * RSTRIDE + h * E_;
  unsigned short* Ko = Kbf + (size_t)(bh * NCH + sc) * CHUNK_USH;
  unsigned short* Vo = VTbf + (size_t)(bh * NCH + sc) * CHUNK_USH;

#pragma unroll
  for (int i = 0; i < 2; ++i) {
    const int j = t + 256 * i;  // 512 16B-blocks
    const int s = j >> 3;
    const int e8 = (j & 7) ^ (s & 7);
    const float* kp = Kb + (size_t)s * RSTRIDE + 8 * e8;
    float4 a = *reinterpret_cast<const float4*>(kp);
    float4 c = *reinterpret_cast<const float4*>(kp + 4);
    *reinterpret_cast<u16x4*>(&Ko[j * 8]) =
        (u16x4){f2bf(a.x), f2bf(a.y), f2bf(a.z), f2bf(a.w)};
    *reinterpret_cast<u16x4*>(&Ko[j * 8 + 4]) =
        (u16x4){f2bf(c.x), f2bf(c.y), f2bf(c.z), f2bf(c.w)};
  }
  {
    const int e = t & 63, w = t >> 6;
#pragma unroll
    for (int i = 0; i < 4; ++i) {
      const int s4 = 4 * w + 16 * i;
      const float* vp = Vb + (size_t)s4 * RSTRIDE + e;
      u16x4 u = {f2bf(vp[0]), f2bf(vp[RSTRIDE]), f2bf(vp[2 * RSTRIDE]),
                 f2bf(vp[3 * RSTRIDE])};
      *reinterpret_cast<u16x4*>(
          &vt[e * 64 + (((s4 >> 3) ^ (e & 7)) << 3) + (s4 & 7)]) = u;
    }
  }
  __syncthreads();
#pragma unroll
  for (int i = 0; i < 2; ++i) {
    const int j = t + 256 * i;  // swizzled space is block-linear
    u16x4 u0 = *reinterpret_cast<const u16x4*>(&vt[j * 8]);
    u16x4 u1 = *reinterpret_cast<const u16x4*>(&vt[j * 8 + 4]);
    *reinterpret_cast<u16x4*>(&Vo[j * 8]) = u0;
    *reinterpret_cast<u16x4*>(&Vo[j * 8 + 4]) = u1;
  }
}

// ---- main: fused, 8 waves = 4 qs x 2 kh, P register-resident ----
__global__ __launch_bounds__(512, 2) void alibi_attn(
    const float* __restrict__ Qg, const unsigned short* __restrict__ Kbf,
    const unsigned short* __restrict__ VTbf, float* __restrict__ Vout,
    float* __restrict__ Pout) {
  __shared__ unsigned short sK[2][2][CHUNK_USH];  // [kh][dbuf] 32KB
  __shared__ unsigned short sV[2][2][CHUNK_USH];  // [kh][dbuf] 32KB
  __shared__ float zbuf[2][4][16];                // [kh][qs][q-col]
  __shared__ float zinv[4][16];                   // [qs][q-row] = 1/z

  const int t = threadIdx.x;
  const int lane = t & 63;
  const int w = t >> 6;   // 0..7
  const int qs = w & 3;   // q-subtile
  const int kh = w >> 2;  // key half: chunks 8*kh .. 8*kh+7
  const int col = lane & 15;
  const int kg = lane >> 4;

  const int id = blockIdx.x;  // id%8 = h -> XCD-pinned scratch in L2
  const int qb = id >> 6;
  const int bh = id & 63;
  const int h = bh & 7;
  const int b = bh >> 3;
  const int q0 = qb * QBLK;

  const float sc_l2e = 0.125f * 1.44269504f;
  const float sl_l2e = exp2f(-(float)(h + 1) * 0.125f) * 1.44269504f;

  const unsigned short* Kc = Kbf + (size_t)bh * NCH * CHUNK_USH;
  const unsigned short* Vc = VTbf + (size_t)bh * NCH * CHUNK_USH;

  // Q B-fragments: q-row = col, k = 8*kg + j (+32 for second slice)
  short8 qf0, qf1;
  {
    const float* qp =
        Qg + ((size_t)b * L_ + q0 + 16 * qs + col) * RSTRIDE + h * E_ + 8 * kg;
    qf0 = ldfrag(qp);
    qf1 = ldfrag(qp + 32);
  }

  const float kbias0 = sl_l2e * (float)(4 * kg - 1023) - 32.0f;

#define STAGE(srcbase, c, dst)                                       \
  {                                                                  \
    const unsigned short* src = (srcbase) + (size_t)(c)*CHUNK_USH;   \
    _Pragma("unroll") for (int i = 0; i < 2; ++i) {                  \
      const int seg = i * 4 + qs;                                    \
      gld16(src + (size_t)(seg * 64 + lane) * 8, (dst) + seg * 512); \
    }                                                                \
  }

  // ===== Loop 1: QK^T + exp + z + PV (unnormalized), single pass =====
  float z0 = 0.f, z1 = 0.f;
  f32x4 oacc[4];
#pragma unroll
  for (int et = 0; et < 4; ++et) oacc[et] = (f32x4){0.f, 0.f, 0.f, 0.f};
  uint2 pw[8][4];  // packed bf16 e-values: [chunk][kt], all static indices

  STAGE(Kc, 8 * kh, sK[kh][0]);
  STAGE(Vc, 8 * kh, sV[kh][0]);
  PIN();
  BAR_VM(0);
#pragma unroll
  for (int c = 0; c < 8; ++c) {
    if (c + 1 < 8) {
      STAGE(Kc, 8 * kh + c + 1, sK[kh][(c + 1) & 1]);
      STAGE(Vc, 8 * kh + c + 1, sV[kh][(c + 1) & 1]);
      PIN();  // issue-early; drained after compute at the barrier
    }
    const int cc = 8 * kh + c;
    const unsigned short* kb = sK[kh][c & 1];
    const unsigned short* vb = sV[kh][c & 1];
#pragma unroll
    for (int kt = 0; kt < 4; ++kt) {
      const int row = 16 * kt + col;
      short8 k0 = *reinterpret_cast<const short8*>(
          &kb[row * 64 + ((kg ^ (row & 7)) << 3)]);
      short8 k1 = *reinterpret_cast<const short8*>(
          &kb[row * 64 + (((kg + 4) ^ (row & 7)) << 3)]);
      f32x4 acc = {0.f, 0.f, 0.f, 0.f};
      acc = __builtin_amdgcn_mfma_f32_16x16x32_bf16(k0, qf0, acc, 0, 0, 0);
      acc = __builtin_amdgcn_mfma_f32_16x16x32_bf16(k1, qf1, acc, 0, 0, 0);
      const float base = fmaf((float)(CHUNK * cc + 16 * kt), sl_l2e, kbias0);
      float e0 = __builtin_amdgcn_exp2f(fmaf(acc[0], sc_l2e, base));
      float e1 = __builtin_amdgcn_exp2f(fmaf(acc[1], sc_l2e, base + sl_l2e));
      float e2 =
          __builtin_amdgcn_exp2f(fmaf(acc[2], sc_l2e, base + 2.f * sl_l2e));
      float e3 =
          __builtin_amdgcn_exp2f(fmaf(acc[3], sc_l2e, base + 3.f * sl_l2e));
      z0 += e0 + e1;
      z1 += e2 + e3;
      const unsigned int b0 = f2bf(e0), b1 = f2bf(e1);
      const unsigned int b2 = f2bf(e2), b3 = f2bf(e3);
      pw[c][kt] = make_uint2(b0 | (b1 << 16), b2 | (b3 << 16));
      // PV with unnormalized e (A-frag k = 4*kg + j == this lane's keys)
      short4v pa = {(short)(unsigned short)b0, (short)(unsigned short)b1,
                    (short)(unsigned short)b2, (short)(unsigned short)b3};
#pragma unroll
      for (int et = 0; et < 4; ++et) {
        const int e = 16 * et + col;
        const int g0 = 2 * kt + (kg >> 1);
        short4v vf = *reinterpret_cast<const short4v*>(
            &vb[e * 64 + ((g0 ^ (e & 7)) << 3) + 4 * (kg & 1)]);
        oacc[et] = mfma16(pa, vf, oacc[et]);
      }
    }
    BAR_VM(0);  // loads of chunk c+1 had the whole compute to land
  }

  // ===== combine z across kg (in-wave) and kh (via LDS) =====
  // NOTE: lane's z / e / P are for q = col (QK D-frag column).
  float z = z0 + z1;
  z += __shfl_xor(z, 16, 64);
  z += __shfl_xor(z, 32, 64);  // all lanes: z-half for q = col
  if (kg == 0) zbuf[kh][qs][col] = z;
  __syncthreads();
  const float minv = 1.0f / (zbuf[0][qs][col] + zbuf[1][qs][col]);  // q = col

  // broadcast per-ROW 1/z for the O path (PV output rows are q = 4*kg+r)
  if (kh == 0 && kg == 0) zinv[qs][col] = minv;

  // ===== combine O across kh (reuse sK as obuf), write O =====
  float* obuf = reinterpret_cast<float*>(&sK[0][0][0]);  // [qs][16][64]
  if (kh == 1) {
#pragma unroll
    for (int et = 0; et < 4; ++et)
#pragma unroll
      for (int r = 0; r < 4; ++r)
        obuf[(qs * 16 + 4 * kg + r) * 64 + 16 * et + col] = oacc[et][r];
  }
  __syncthreads();
  if (kh == 0) {
    float minvR[4];
#pragma unroll
    for (int r = 0; r < 4; ++r) minvR[r] = zinv[qs][4 * kg + r];
    float* Vo = Vout + (((size_t)b * L_ + q0 + 16 * qs) * H_ + h) * E_;
#pragma unroll
    for (int et = 0; et < 4; ++et) {
#pragma unroll
      for (int r = 0; r < 4; ++r) {
        const float o =
            (oacc[et][r] + obuf[(qs * 16 + 4 * kg + r) * 64 + 16 * et + col]) *
            minvR[r];
        __builtin_nontemporal_store(
            o, &Vo[(4 * kg + r) * RSTRIDE + 16 * et + col]);
      }
    }
  }

  // ===== Loop 2: pure store stream, P = e * minv (q = col) — PLAIN stores ==
  float* Pb = Pout + ((size_t)(b * H_ + h) * L_ + q0 + 16 * qs + col) * L_ +
              4 * kg;
#pragma unroll
  for (int c = 0; c < 8; ++c) {
    const int cc = 8 * kh + c;
#pragma unroll
    for (int kt = 0; kt < 4; ++kt) {
      const uint2 u = pw[c][kt];
      f32x4 out;
      out[0] = bf2f(u.x & 0xffffu) * minv;
      out[1] = bf2f(u.x >> 16) * minv;
      out[2] = bf2f(u.y & 0xffffu) * minv;
      out[3] = bf2f(u.y >> 16) * minv;
      *reinterpret_cast<f32x4*>(Pb + CHUNK * cc + 16 * kt) = out;
    }
  }
}

extern "C" void kernel_launch(void* const* d_in, const int* in_sizes, int n_in,
                              void* d_out, int out_size, void* d_ws,
                              size_t ws_size, hipStream_t stream) {
  const float* Q = (const float*)d_in[0];
  const float* K = (const float*)d_in[1];
  const float* V = (const float*)d_in[2];
  float* out = (float*)d_out;
  float* Vo = out;                              // [B,L,H,E]
  float* Po = out + (size_t)B_ * L_ * H_ * E_;  // [B,H,L,L]
  unsigned short* Kbf = (unsigned short*)d_ws;  // 8 MB
  unsigned short* VTbf = Kbf + (size_t)B_ * H_ * L_ * E_;  // 8 MB
  hipLaunchKernelGGL(prep_kv, dim3(NCH * B_ * H_), dim3(256), 0, stream, K, V,
                     Kbf, VTbf);
  hipLaunchKernelGGL(alibi_attn, dim3((L_ / QBLK) * H_ * B_), dim3(512), 0,
                     stream, Q, Kbf, VTbf, Vo, Po);
}

// Round 18
// 97.826 us; speedup vs baseline: 1.2994x; 1.1477x over previous
//
#include <hip/hip_runtime.h>
#include <hip/hip_bf16.h>

// ALiBi attention, B=8 L=1024 H=8 E=64, fp32 in/out, bf16 MFMA inside.
// Outputs: V [B,L,H,E] then series [B,H,L,L] concatenated in d_out.
// R18 = R12 (best: 95.4us) + pass-A prefetch depth 3 (all 4 K-buffers:
// compute c, landed c+1, in-flight c+2 and c+3; counted vmcnt 4/2/0).
// Geometry: CHUNK=64, 4 waves x 16 q-rows, grid 1024, 32KB LDS, 4 blk/CU.
// Pass B unchanged: 2K+2V dbuf, issue-4/vmcnt(4), register-resident P
// (QK D-frag == 16x16x16 A-frag), fixed-max softmax, XCD-pinned scratch.

typedef short short8 __attribute__((ext_vector_type(8)));
typedef short short4v __attribute__((ext_vector_type(4)));
typedef float f32x4 __attribute__((ext_vector_type(4)));
typedef unsigned short u16x4 __attribute__((ext_vector_type(4)));

#define B_ 8
#define L_ 1024
#define H_ 8
#define E_ 64
#define RSTRIDE (H_ * E_)       // 512 floats between seq rows
#define QBLK 64                 // 4 waves x 16 q-rows
#define CHUNK 64                // keys per chunk
#define NCH (L_ / CHUNK)        // 16
#define CHUNK_USH (CHUNK * E_)  // 4096 ushorts = 8KB per chunk tile

__device__ __forceinline__ unsigned short f2bf(float f) {
  return __builtin_bit_cast(unsigned short, __float2bfloat16(f));
}
__device__ __forceinline__ short8 ldfrag(const float* p) {
  float4 a = *reinterpret_cast<const float4*>(p);
  float4 b = *reinterpret_cast<const float4*>(p + 4);
  return (short8){(short)f2bf(a.x), (short)f2bf(a.y), (short)f2bf(a.z),
                  (short)f2bf(a.w), (short)f2bf(b.x), (short)f2bf(b.y),
                  (short)f2bf(b.z), (short)f2bf(b.w)};
}

__device__ __forceinline__ f32x4 mfma16(short4v a, short4v b, f32x4 c) {
#if __has_builtin(__builtin_amdgcn_mfma_f32_16x16x16bf16_1k)
  return __builtin_amdgcn_mfma_f32_16x16x16bf16_1k(a, b, c, 0, 0, 0);
#else
  asm volatile(
      "s_nop 1\n\t"
      "v_mfma_f32_16x16x16_bf16 %0, %1, %2, %0\n\t"
      "s_nop 2"
      : "+v"(c)
      : "v"(a), "v"(b));
  return c;
#endif
}

__device__ __forceinline__ void gld16(const unsigned short* g,
                                      unsigned short* l) {
  __builtin_amdgcn_global_load_lds(
      (const __attribute__((address_space(1))) unsigned int*)g,
      (__attribute__((address_space(3))) unsigned int*)l, 16, 0, 0);
}

// counted-vmcnt barrier: the N newest VMEM ops may stay in flight
#define BAR_VM(N)                                         \
  {                                                       \
    asm volatile("s_waitcnt vmcnt(" #N ")" ::: "memory"); \
    __builtin_amdgcn_s_barrier();                         \
    __builtin_amdgcn_sched_barrier(0);                    \
  }
#define PIN() __builtin_amdgcn_sched_barrier(0)

// ---- prep: scratch in gload-linear swizzled block order ----
// K chunk (64 s x 64 e): 16B-block j <-> (s = j>>3, e8 = (j&7)^(s&7)).
// VT chunk (64 e x 64 s): block j <-> (e = j>>3, g = (j&7)^(e&7)).
__global__ __launch_bounds__(256, 4) void prep_kv(
    const float* __restrict__ Kg, const float* __restrict__ Vg,
    unsigned short* __restrict__ Kbf, unsigned short* __restrict__ VTbf) {
  __shared__ unsigned short vt[64 * 64];  // V^T tile in swizzled space

  const int t = threadIdx.x;
  const int id = blockIdx.x;
  const int bh = id & 63;  // id%8 = h -> same XCD as consumers
  const int sc = id >> 6;  // chunk 0..15
  const int h = bh & 7, b = bh >> 3;
  const int s0 = sc * CHUNK;

  const float* Kb = Kg + ((size_t)b * L_ + s0) * RSTRIDE + h * E_;
  const float* Vb = Vg + ((size_t)b * L_ + s0) * RSTRIDE + h * E_;
  unsigned short* Ko = Kbf + (size_t)(bh * NCH + sc) * CHUNK_USH;
  unsigned short* Vo = VTbf + (size_t)(bh * NCH + sc) * CHUNK_USH;

  // K: direct convert into swizzled block order (reads stay coalesced)
#pragma unroll
  for (int i = 0; i < 2; ++i) {
    const int j = t + 256 * i;  // 512 blocks
    const int s = j >> 3;
    const int e8 = (j & 7) ^ (s & 7);
    const float* kp = Kb + (size_t)s * RSTRIDE + 8 * e8;
    float4 a = *reinterpret_cast<const float4*>(kp);
    float4 c = *reinterpret_cast<const float4*>(kp + 4);
    *reinterpret_cast<u16x4*>(&Ko[j * 8]) =
        (u16x4){f2bf(a.x), f2bf(a.y), f2bf(a.z), f2bf(a.w)};
    *reinterpret_cast<u16x4*>(&Ko[j * 8 + 4]) =
        (u16x4){f2bf(c.x), f2bf(c.y), f2bf(c.z), f2bf(c.w)};
  }
  // V: transpose through LDS (swizzled space), then linear copy out
  {
    const int e = t & 63, w = t >> 6;
#pragma unroll
    for (int i = 0; i < 4; ++i) {
      const int s4 = 4 * w + 16 * i;
      const float* vp = Vb + (size_t)s4 * RSTRIDE + e;
      u16x4 u = {f2bf(vp[0]), f2bf(vp[RSTRIDE]), f2bf(vp[2 * RSTRIDE]),
                 f2bf(vp[3 * RSTRIDE])};
      *reinterpret_cast<u16x4*>(
          &vt[e * 64 + (((s4 >> 3) ^ (e & 7)) << 3) + (s4 & 7)]) = u;
    }
  }
  __syncthreads();
#pragma unroll
  for (int i = 0; i < 2; ++i) {
    const int j = t + 256 * i;  // swizzled space is already block-linear
    u16x4 u0 = *reinterpret_cast<const u16x4*>(&vt[j * 8]);
    u16x4 u1 = *reinterpret_cast<const u16x4*>(&vt[j * 8 + 4]);
    *reinterpret_cast<u16x4*>(&Vo[j * 8]) = u0;
    *reinterpret_cast<u16x4*>(&Vo[j * 8 + 4]) = u1;
  }
}

// ---- main: 4 waves x 16 q-rows, counted-vmcnt pipelined staging ----
__global__ __launch_bounds__(256, 4) void alibi_attn(
    const float* __restrict__ Qg, const unsigned short* __restrict__ Kbf,
    const unsigned short* __restrict__ VTbf, float* __restrict__ Vout,
    float* __restrict__ Pout) {
  // 32KB union: pass A = 4 K-buffers; pass B = K in [0],[1], VT in [2],[3]
  __shared__ unsigned short sBuf[4][CHUNK_USH];

  const int t = threadIdx.x;
  const int lane = t & 63;
  const int w = t >> 6;
  const int col = lane & 15;
  const int kg = lane >> 4;

  const int id = blockIdx.x;  // id%8 = h -> XCD-pinned scratch in L2
  const int qb = id >> 6;
  const int bh = id & 63;
  const int h = bh & 7;
  const int b = bh >> 3;
  const int q0 = qb * QBLK;

  const float sc_l2e = 0.125f * 1.44269504f;
  const float sl_l2e = exp2f(-(float)(h + 1) * 0.125f) * 1.44269504f;

  const unsigned short* Kc = Kbf + (size_t)bh * NCH * CHUNK_USH;
  const unsigned short* Vc = VTbf + (size_t)bh * NCH * CHUNK_USH;

  // Q B-fragments: q-row = col, k = 8*kg + j (+32 for second slice)
  short8 qf0, qf1;
  {
    const float* qp =
        Qg + ((size_t)b * L_ + q0 + 16 * w + col) * RSTRIDE + h * E_ + 8 * kg;
    qf0 = ldfrag(qp);
    qf1 = ldfrag(qp + 32);
  }

  const float kbias0 = sl_l2e * (float)(4 * kg - 1023) - 32.0f;

  // stage one 8KB chunk: 2 x gld16 per thread (segs w, w+4)
#define STAGE(srcbase, c, dst)                                       \
  {                                                                  \
    const unsigned short* src = (srcbase) + (size_t)(c)*CHUNK_USH;   \
    _Pragma("unroll") for (int i = 0; i < 2; ++i) {                  \
      const int seg = i * 4 + w;                                     \
      gld16(src + (size_t)(seg * 64 + lane) * 8, (dst) + seg * 512); \
    }                                                                \
  }

  // ===== Pass A: z = sum exp2(u-32); 4 bufs, depth-3 prefetch =====
  float z0 = 0.f, z1 = 0.f, z2 = 0.f, z3 = 0.f;
  STAGE(Kc, 0, sBuf[0]);
  STAGE(Kc, 1, sBuf[1]);
  STAGE(Kc, 2, sBuf[2]);
  PIN();
  BAR_VM(4);  // chunk 0 landed; chunks 1,2 (4 loads) in flight
  for (int c = 0; c < NCH; ++c) {
    if (c + 3 < NCH) {
      STAGE(Kc, c + 3, sBuf[(c + 3) & 3]);
      PIN();
    }
    const unsigned short* kb = sBuf[c & 3];
#pragma unroll
    for (int kt = 0; kt < 4; ++kt) {
      const int row = 16 * kt + col;
      short8 k0 = *reinterpret_cast<const short8*>(
          &kb[row * 64 + ((kg ^ (row & 7)) << 3)]);
      short8 k1 = *reinterpret_cast<const short8*>(
          &kb[row * 64 + (((kg + 4) ^ (row & 7)) << 3)]);
      f32x4 acc = {0.f, 0.f, 0.f, 0.f};
      acc = __builtin_amdgcn_mfma_f32_16x16x32_bf16(k0, qf0, acc, 0, 0, 0);
      acc = __builtin_amdgcn_mfma_f32_16x16x32_bf16(k1, qf1, acc, 0, 0, 0);
      const float base = fmaf((float)(CHUNK * c + 16 * kt), sl_l2e, kbias0);
      z0 += __builtin_amdgcn_exp2f(fmaf(acc[0], sc_l2e, base));
      z1 += __builtin_amdgcn_exp2f(fmaf(acc[1], sc_l2e, base + sl_l2e));
      z2 += __builtin_amdgcn_exp2f(fmaf(acc[2], sc_l2e, base + 2.f * sl_l2e));
      z3 += __builtin_amdgcn_exp2f(fmaf(acc[3], sc_l2e, base + 3.f * sl_l2e));
    }
    // need chunk c+1 landed. In-flight loads after this iter's compute:
    // stages c+2 (issued iter c-1) and c+3 (issued iter c), 2 loads each.
    if (c + 3 < NCH) {
      BAR_VM(4);
    } else if (c + 2 < NCH) {
      BAR_VM(2);
    } else {
      BAR_VM(0);
    }
  }
  float z = (z0 + z1) + (z2 + z3);
  z += __shfl_xor(z, 16, 64);
  z += __shfl_xor(z, 32, 64);
  const float minv = 1.0f / z;

  // ===== Pass B: 2K+2V buffers, issue-4 / vmcnt(4) =====
  f32x4 oacc[4];
#pragma unroll
  for (int et = 0; et < 4; ++et) oacc[et] = (f32x4){0.f, 0.f, 0.f, 0.f};

  float* Pb =
      Pout + ((size_t)(b * H_ + h) * L_ + q0 + 16 * w + col) * L_ + 4 * kg;

  __syncthreads();  // pass A fully done before buffer repurposing
  STAGE(Kc, 0, sBuf[0]);
  STAGE(Vc, 0, sBuf[2]);
  PIN();
  BAR_VM(0);
  for (int c = 0; c < NCH; ++c) {
    if (c + 1 < NCH) {
      STAGE(Kc, c + 1, sBuf[(c + 1) & 1]);
      STAGE(Vc, c + 1, sBuf[2 + ((c + 1) & 1)]);
      PIN();  // pin the 4 loads ahead of this iteration's 4 P-stores
    }
    const unsigned short* kb = sBuf[c & 1];
    const unsigned short* vb = sBuf[2 + (c & 1)];
#pragma unroll
    for (int kt = 0; kt < 4; ++kt) {
      const int row = 16 * kt + col;
      short8 k0 = *reinterpret_cast<const short8*>(
          &kb[row * 64 + ((kg ^ (row & 7)) << 3)]);
      short8 k1 = *reinterpret_cast<const short8*>(
          &kb[row * 64 + (((kg + 4) ^ (row & 7)) << 3)]);
      f32x4 acc = {0.f, 0.f, 0.f, 0.f};
      acc = __builtin_amdgcn_mfma_f32_16x16x32_bf16(k0, qf0, acc, 0, 0, 0);
      acc = __builtin_amdgcn_mfma_f32_16x16x32_bf16(k1, qf1, acc, 0, 0, 0);
      // V^T fragments from LDS: e = 16et+col, s-block g0 = 2kt + (kg>>1)
      short4v vf[4];
      const int g0 = 2 * kt + (kg >> 1);
      const int so = 4 * (kg & 1);
#pragma unroll
      for (int et = 0; et < 4; ++et) {
        const int e = 16 * et + col;
        vf[et] = *reinterpret_cast<const short4v*>(
            &vb[e * 64 + ((g0 ^ (e & 7)) << 3) + so]);
      }
      const float base = fmaf((float)(CHUNK * c + 16 * kt), sl_l2e, kbias0);
      f32x4 pf;
      pf[0] = __builtin_amdgcn_exp2f(fmaf(acc[0], sc_l2e, base)) * minv;
      pf[1] =
          __builtin_amdgcn_exp2f(fmaf(acc[1], sc_l2e, base + sl_l2e)) * minv;
      pf[2] = __builtin_amdgcn_exp2f(fmaf(acc[2], sc_l2e, base + 2.f * sl_l2e)) *
              minv;
      pf[3] = __builtin_amdgcn_exp2f(fmaf(acc[3], sc_l2e, base + 3.f * sl_l2e)) *
              minv;
      // P store straight from D-frag (stays in flight across the barrier)
      *reinterpret_cast<f32x4*>(Pb + CHUNK * c + 16 * kt) = pf;
      // pack to bf16 A-frag (k = 4*kg + j == this lane's keys) and PV
      short4v pa = {(short)f2bf(pf[0]), (short)f2bf(pf[1]), (short)f2bf(pf[2]),
                    (short)f2bf(pf[3])};
#pragma unroll
      for (int et = 0; et < 4; ++et) oacc[et] = mfma16(pa, vf[et], oacc[et]);
    }
    // program order per iter (pinned): [4 stage loads][4 P-stores].
    // vmcnt(4): waits for the loads, leaves only the stores in flight.
    BAR_VM(4);
  }

  // ---- write O: q = q0+16w+4kg+r, e = 16et+col ----
  float* Vo = Vout + (((size_t)b * L_ + q0 + 16 * w) * H_ + h) * E_;
#pragma unroll
  for (int et = 0; et < 4; ++et) {
#pragma unroll
    for (int r = 0; r < 4; ++r) {
      __builtin_nontemporal_store(oacc[et][r],
                                  &Vo[(4 * kg + r) * RSTRIDE + 16 * et + col]);
    }
  }
}

extern "C" void kernel_launch(void* const* d_in, const int* in_sizes, int n_in,
                              void* d_out, int out_size, void* d_ws,
                              size_t ws_size, hipStream_t stream) {
  const float* Q = (const float*)d_in[0];
  const float* K = (const float*)d_in[1];
  const float* V = (const float*)d_in[2];
  float* out = (float*)d_out;
  float* Vo = out;                              // [B,L,H,E]
  float* Po = out + (size_t)B_ * L_ * H_ * E_;  // [B,H,L,L]
  unsigned short* Kbf = (unsigned short*)d_ws;  // 8 MB
  unsigned short* VTbf = Kbf + (size_t)B_ * H_ * L_ * E_;  // 8 MB
  hipLaunchKernelGGL(prep_kv, dim3(NCH * B_ * H_), dim3(256), 0, stream, K, V,
                     Kbf, VTbf);
  hipLaunchKernelGGL(alibi_attn, dim3((L_ / QBLK) * H_ * B_), dim3(256), 0,
                     stream, Q, Kbf, VTbf, Vo, Po);
}